// Round 1
// baseline (1798.395 us; speedup 1.0000x reference)
//
#include <hip/hip_runtime.h>
#include <cstddef>

// Problem constants (from reference): T=1024, B=64, DIM=512, N=64
#define T_STEPS 1024
#define BATCH   64
#define DIMK    512
#define NDIM    64
#define PROJW   256   // 4*N

__device__ __forceinline__ float sigmoidf_(float x) {
    return 1.0f / (1.0f + __expf(-x));
}

// ---------------------------------------------------------------------------
// Kernel 1: projection GEMM  C[M=T*B][256] = X[M][512] * W[256][512]^T
// Both operands are K-contiguous (row-major, K inner) -> "NT" dot-of-rows GEMM.
// Tiling: BM=64, BN=64, BK=32; block 256 threads; each thread 4x4 outputs.
// LDS tiles stored k-major with +1-pad (65) -> <=2-way bank aliasing (free).
// ---------------------------------------------------------------------------
__global__ __launch_bounds__(256) void proj_gemm(const float* __restrict__ X,
                                                 const float* __restrict__ W,
                                                 float* __restrict__ C) {
    __shared__ float As[32][65];
    __shared__ float Bs[32][65];
    const int tid  = threadIdx.x;
    const int row0 = blockIdx.x * 64;   // 1024 row-tiles
    const int col0 = blockIdx.y * 64;   // 4 col-tiles
    const int tx = tid & 15, ty = tid >> 4;
    const int lm = tid >> 3;            // 0..31
    const int lk = (tid & 7) << 2;      // 0,4,...,28

    float acc[4][4] = {};

    for (int kb = 0; kb < DIMK; kb += 32) {
        // coalesced global loads: 8 consecutive threads cover one row's 32 k's
        const float4 a0 = *(const float4*)&X[(size_t)(row0 + lm)      * DIMK + kb + lk];
        const float4 a1 = *(const float4*)&X[(size_t)(row0 + lm + 32) * DIMK + kb + lk];
        const float4 b0 = *(const float4*)&W[(size_t)(col0 + lm)      * DIMK + kb + lk];
        const float4 b1 = *(const float4*)&W[(size_t)(col0 + lm + 32) * DIMK + kb + lk];
        __syncthreads();   // previous iteration's readers done
        As[lk+0][lm]    = a0.x; As[lk+1][lm]    = a0.y; As[lk+2][lm]    = a0.z; As[lk+3][lm]    = a0.w;
        As[lk+0][lm+32] = a1.x; As[lk+1][lm+32] = a1.y; As[lk+2][lm+32] = a1.z; As[lk+3][lm+32] = a1.w;
        Bs[lk+0][lm]    = b0.x; Bs[lk+1][lm]    = b0.y; Bs[lk+2][lm]    = b0.z; Bs[lk+3][lm]    = b0.w;
        Bs[lk+0][lm+32] = b1.x; Bs[lk+1][lm+32] = b1.y; Bs[lk+2][lm+32] = b1.z; Bs[lk+3][lm+32] = b1.w;
        __syncthreads();
        #pragma unroll 8
        for (int k = 0; k < 32; ++k) {
            const float4 av = *(const float4*)&As[k][ty << 2];  // broadcast (4 addrs/wave)
            const float4 bv = *(const float4*)&Bs[k][tx << 2];  // 2-way aliasing (free)
            const float a[4]  = {av.x, av.y, av.z, av.w};
            const float bb[4] = {bv.x, bv.y, bv.z, bv.w};
            #pragma unroll
            for (int i2 = 0; i2 < 4; ++i2)
                #pragma unroll
                for (int j2 = 0; j2 < 4; ++j2)
                    acc[i2][j2] = fmaf(a[i2], bb[j2], acc[i2][j2]);
        }
    }
    #pragma unroll
    for (int i2 = 0; i2 < 4; ++i2) {
        float4 o = {acc[i2][0], acc[i2][1], acc[i2][2], acc[i2][3]};
        *(float4*)&C[(size_t)(row0 + (ty << 2) + i2) * PROJW + col0 + (tx << 2)] = o;
    }
}

// ---------------------------------------------------------------------------
// Kernel 2: sequential recurrence.
// The scan step is row-independent given the shared per-step vectors
// (k_norm, v, q, m_norm), so we split the 64x64 state of each batch into
// 16-row tiles: grid = 64 batches * 4 row-tiles = 256 blocks (1 per CU).
// Block = 256 threads: 16 rows x 16 lanes; each lane owns 4 columns of its
// row of S and M in registers for the whole 1024-step loop.
// Per step: stage the 256-float proj slice in LDS; raw (unnormalized) dots
// overlap the 64-lane norm butterflies; scale by inverse norms afterwards.
// ---------------------------------------------------------------------------
__global__ __launch_bounds__(256) void recur_kernel(const float* __restrict__ proj,
                                                    const float* __restrict__ S0,
                                                    const float* __restrict__ M0,
                                                    const float* __restrict__ BSmat,
                                                    const float* __restrict__ BMmat,
                                                    float* __restrict__ outp,
                                                    float* __restrict__ Sout,
                                                    float* __restrict__ Mout) {
    const int tid  = threadIdx.x;
    const int b    = blockIdx.x >> 2;    // batch
    const int rt   = blockIdx.x & 3;     // row tile (16 rows)
    const int rl   = tid >> 4;           // local row 0..15
    const int i    = (rt << 4) + rl;     // global row 0..63
    const int l16  = tid & 15;           // lane within row group
    const int j0   = l16 << 2;           // first of 4 owned columns
    const int lane = tid & 63;

    __shared__ float shv[256];           // [k(64) | v(64) | q(64) | m(64)]

    float S[4], Mr[4], BSr[4], BMr[4];
    const size_t smoff = ((size_t)b * NDIM + i) * NDIM + j0;
    { float4 t4 = *(const float4*)&S0[smoff];                        S[0]=t4.x;  S[1]=t4.y;  S[2]=t4.z;  S[3]=t4.w;  }
    { float4 t4 = *(const float4*)&M0[smoff];                        Mr[0]=t4.x; Mr[1]=t4.y; Mr[2]=t4.z; Mr[3]=t4.w; }
    { float4 t4 = *(const float4*)&BSmat[(size_t)i * NDIM + j0];     BSr[0]=t4.x;BSr[1]=t4.y;BSr[2]=t4.z;BSr[3]=t4.w;}
    { float4 t4 = *(const float4*)&BMmat[(size_t)i * NDIM + j0];     BMr[0]=t4.x;BMr[1]=t4.y;BMr[2]=t4.z;BMr[3]=t4.w;}

    const float* pbase = proj + (size_t)b * PROJW + tid;  // proj[t][b][tid]
    float nxt = pbase[0];

    for (int t = 0; t < T_STEPS; ++t) {
        shv[tid] = nxt;
        __syncthreads();
        if (t + 1 < T_STEPS) nxt = pbase[(size_t)(t + 1) * BATCH * PROJW];  // prefetch

        // ---- gather step vectors from LDS ----
        float kk = shv[lane];          // for ||k|| (redundant per wave)
        float mm = shv[192 + lane];    // for ||m||
        const float4 k4 = *(const float4*)&shv[j0];
        const float4 q4 = *(const float4*)&shv[128 + j0];
        const float4 m4 = *(const float4*)&shv[192 + j0];
        const float v_i = shv[64 + i];
        const float kr[4] = {k4.x, k4.y, k4.z, k4.w};
        const float qr[4] = {q4.x, q4.y, q4.z, q4.w};
        const float mr[4] = {m4.x, m4.y, m4.z, m4.w};

        // ---- raw dots on OLD S, M (unnormalized; scaled later) ----
        float Mk = 0.f, Sk = 0.f, Mm = 0.f;
        #pragma unroll
        for (int c = 0; c < 4; ++c) {
            Mk = fmaf(Mr[c], kr[c], Mk);
            Sk = fmaf(S[c],  kr[c], Sk);
            Mm = fmaf(Mr[c], mr[c], Mm);
        }
        // 16-lane butterflies (overlap with the 64-lane norm butterflies below)
        #pragma unroll
        for (int d = 1; d < 16; d <<= 1) {
            Mk += __shfl_xor(Mk, d);
            Sk += __shfl_xor(Sk, d);
            Mm += __shfl_xor(Mm, d);
        }
        // ---- norms (every wave computes both redundantly; no extra barrier) ----
        float sk2 = kk * kk, sm2 = mm * mm;
        #pragma unroll
        for (int d = 1; d < 64; d <<= 1) {
            sk2 += __shfl_xor(sk2, d);
            sm2 += __shfl_xor(sm2, d);
        }
        const float inv_k = 1.0f / (sqrtf(sk2) + 1e-6f);
        const float inv_m = 1.0f / (sqrtf(sm2) + 1e-6f);

        float kn[4], mn[4];
        #pragma unroll
        for (int c = 0; c < 4; ++c) { kn[c] = kr[c] * inv_k; mn[c] = mr[c] * inv_m; }
        Mk *= inv_k; Sk *= inv_k; Mm *= inv_m;
        const float sd = v_i - Sk;                 // s_delta[i]

        // ---- G_S and S update ----
        #pragma unroll
        for (int c = 0; c < 4; ++c) {
            const float gs = sigmoidf_(fmaf(Mk, kn[c], Mr[c]) + BSr[c]);
            S[c] = fmaf(gs, S[c], sd * kn[c]);
        }
        // ---- dots on NEW S ----
        float Sm = 0.f, Sq = 0.f;
        #pragma unroll
        for (int c = 0; c < 4; ++c) {
            Sm = fmaf(S[c], mn[c], Sm);
            Sq = fmaf(S[c], qr[c], Sq);
        }
        #pragma unroll
        for (int d = 1; d < 16; d <<= 1) {
            Sm += __shfl_xor(Sm, d);
            Sq += __shfl_xor(Sq, d);
        }
        const float md = sd - Mm;                  // m_delta[i]

        // ---- G_M and M update ----
        #pragma unroll
        for (int c = 0; c < 4; ++c) {
            const float gm = sigmoidf_(fmaf(Sm, mn[c], S[c]) + BMr[c]);
            Mr[c] = fmaf(gm, Mr[c], md * mn[c]);
        }
        // ---- output: Sq^2 * sigmoid(Sq) ----
        if (l16 == 0) {
            outp[(size_t)t * (BATCH * NDIM) + b * NDIM + i] = Sq * Sq * sigmoidf_(Sq);
        }
        __syncthreads();   // protect shv before next iteration's store
    }

    { float4 o = {S[0], S[1], S[2], S[3]};     *(float4*)&Sout[smoff] = o; }
    { float4 o = {Mr[0], Mr[1], Mr[2], Mr[3]}; *(float4*)&Mout[smoff] = o; }
}

// ---------------------------------------------------------------------------
extern "C" void kernel_launch(void* const* d_in, const int* in_sizes, int n_in,
                              void* d_out, int out_size, void* d_ws, size_t ws_size,
                              hipStream_t stream) {
    const float* x   = (const float*)d_in[0];   // (T,B,DIM) f32
    const float* S0  = (const float*)d_in[1];   // (B,N,N)
    const float* M0  = (const float*)d_in[2];   // (B,N,N)
    const float* W   = (const float*)d_in[3];   // (4N,DIM)
    const float* BS  = (const float*)d_in[4];   // (N,N)
    const float* BMb = (const float*)d_in[5];   // (N,N)
    float* out = (float*)d_out;

    // workspace: proj = T*B*256 f32 = 64 MB
    float* proj = (float*)d_ws;

    dim3 g1(1024, 4), b1(256);
    proj_gemm<<<g1, b1, 0, stream>>>(x, W, proj);

    float* Sout = out + (size_t)T_STEPS * BATCH * NDIM;
    float* Mout = Sout + (size_t)BATCH * NDIM * NDIM;
    recur_kernel<<<dim3(BATCH * 4), dim3(256), 0, stream>>>(proj, S0, M0, BS, BMb,
                                                            out, Sout, Mout);
}

// Round 5
// 865.753 us; speedup vs baseline: 2.0773x; 2.0773x over previous
//
#include <hip/hip_runtime.h>
#include <cstddef>

// Problem constants (from reference): T=1024, B=64, DIM=512, N=64
#define T_STEPS 1024
#define BATCH   64
#define DIMK    512
#define NDIM    64
#define PROJW   256   // 4*N
#define STEPSTRIDE (BATCH * PROJW)

__device__ __forceinline__ float sigmoidf_(float x) {
    return 1.0f / (1.0f + __expf(-x));
}

// DPP row-rotate move: dst lane i <- src lane (i+N) mod 16 (within each 16-lane row)
template<int CTRL>
__device__ __forceinline__ float dpp_mov(float x) {
    return __int_as_float(__builtin_amdgcn_update_dpp(
        0, __float_as_int(x), CTRL, 0xF, 0xF, true));
}
// 16-lane allreduce sum via rotations 8,4,2,1 (row_ror ctrl = 0x120|N).
__device__ __forceinline__ float rowsum16(float x) {
    x += dpp_mov<0x128>(x);
    x += dpp_mov<0x124>(x);
    x += dpp_mov<0x122>(x);
    x += dpp_mov<0x121>(x);
    return x;
}

// ---------------------------------------------------------------------------
// Kernel 1: projection GEMM  C[M=T*B][256] = X[M][512] * W[256][512]^T
// 128x128 tile, BK=16, 256 threads, 8x8 acc/thread in 2x2 blocked-cyclic
// fragment layout (rows ty*4+r & 64+ty*4+r; cols tx*4+c & 64+tx*4+c).
// All LDS reads conflict-free by construction: A-reads 4 distinct addrs in 4
// distinct bank-groups (rest broadcast); B-reads 16 distinct addrs, 2
// lanes/bank (free); staging writes 2 lanes/bank. Global prefetch for tile
// t+1 issued before compute of tile t (latency hidden under 2048-cyc VALU).
// ---------------------------------------------------------------------------
__global__ __launch_bounds__(256) void proj_gemm(const float* __restrict__ X,
                                                 const float* __restrict__ W,
                                                 float* __restrict__ C) {
    __shared__ float As[16][132];
    __shared__ float Bs[16][132];
    const int tid  = threadIdx.x;
    const int row0 = blockIdx.x * 128;            // 512 row tiles
    const int col0 = blockIdx.y * 128;            // 2 col tiles
    const int tx4  = (tid & 15) << 2;
    const int ty4  = (tid >> 4) << 2;
    const int lm   = tid >> 2;                    // 0..63 staging row
    const int lk   = (tid & 3) << 2;              // 0,4,8,12 staging k

    const float* Arow0 = X + (size_t)(row0 + lm)      * DIMK + lk;
    const float* Arow1 = X + (size_t)(row0 + lm + 64) * DIMK + lk;
    const float* Brow0 = W + (size_t)(col0 + lm)      * DIMK + lk;
    const float* Brow1 = W + (size_t)(col0 + lm + 64) * DIMK + lk;

    float acc[8][8] = {};
    float4 pa0, pa1, pb0, pb1;

    pa0 = *(const float4*)(Arow0);
    pa1 = *(const float4*)(Arow1);
    pb0 = *(const float4*)(Brow0);
    pb1 = *(const float4*)(Brow1);

    for (int tile = 0; tile < DIMK / 16; ++tile) {
        __syncthreads();   // previous tile's readers done
        As[lk+0][lm]    = pa0.x; As[lk+1][lm]    = pa0.y; As[lk+2][lm]    = pa0.z; As[lk+3][lm]    = pa0.w;
        As[lk+0][lm+64] = pa1.x; As[lk+1][lm+64] = pa1.y; As[lk+2][lm+64] = pa1.z; As[lk+3][lm+64] = pa1.w;
        Bs[lk+0][lm]    = pb0.x; Bs[lk+1][lm]    = pb0.y; Bs[lk+2][lm]    = pb0.z; Bs[lk+3][lm]    = pb0.w;
        Bs[lk+0][lm+64] = pb1.x; Bs[lk+1][lm+64] = pb1.y; Bs[lk+2][lm+64] = pb1.z; Bs[lk+3][lm+64] = pb1.w;
        __syncthreads();
        if (tile + 1 < DIMK / 16) {
            const int kb = (tile + 1) * 16;
            pa0 = *(const float4*)(Arow0 + kb);
            pa1 = *(const float4*)(Arow1 + kb);
            pb0 = *(const float4*)(Brow0 + kb);
            pb1 = *(const float4*)(Brow1 + kb);
        }
        #pragma unroll 8
        for (int k = 0; k < 16; ++k) {
            const float4 a0v = *(const float4*)&As[k][ty4];
            const float4 a1v = *(const float4*)&As[k][64 + ty4];
            const float4 b0v = *(const float4*)&Bs[k][tx4];
            const float4 b1v = *(const float4*)&Bs[k][64 + tx4];
            const float a[8]  = {a0v.x, a0v.y, a0v.z, a0v.w, a1v.x, a1v.y, a1v.z, a1v.w};
            const float bb[8] = {b0v.x, b0v.y, b0v.z, b0v.w, b1v.x, b1v.y, b1v.z, b1v.w};
            #pragma unroll
            for (int i2 = 0; i2 < 8; ++i2)
                #pragma unroll
                for (int j2 = 0; j2 < 8; ++j2)
                    acc[i2][j2] = fmaf(a[i2], bb[j2], acc[i2][j2]);
        }
    }

    #pragma unroll
    for (int h = 0; h < 2; ++h) {
        #pragma unroll
        for (int r = 0; r < 4; ++r) {
            const size_t R = (size_t)(row0 + h * 64 + ty4 + r) * PROJW + col0;
            float4 o0 = {acc[h*4+r][0], acc[h*4+r][1], acc[h*4+r][2], acc[h*4+r][3]};
            float4 o1 = {acc[h*4+r][4], acc[h*4+r][5], acc[h*4+r][6], acc[h*4+r][7]};
            *(float4*)&C[R + tx4]      = o0;
            *(float4*)&C[R + 64 + tx4] = o1;
        }
    }
}

// ---------------------------------------------------------------------------
// Kernel 1.5: normalize k (cols 0..63) and m (cols 192..255) of proj in place.
// Norms depend only on proj -> fully parallel over (t,b); removes the 64-lane
// reduction + sqrt/div from the sequential scan's critical path.
// One 64-lane wave per (t,b) pair; 4 pairs per 256-thread block.
// ---------------------------------------------------------------------------
__global__ __launch_bounds__(256) void normalize_km(float* __restrict__ proj) {
    const int p    = blockIdx.x * 4 + (threadIdx.x >> 6);  // (t,b) pair index
    const int lane = threadIdx.x & 63;
    float* base = proj + (size_t)p * PROJW;
    const float k = base[lane];
    const float m = base[192 + lane];
    float sk = k * k, sm = m * m;
    #pragma unroll
    for (int d = 1; d < 64; d <<= 1) {
        sk += __shfl_xor(sk, d);
        sm += __shfl_xor(sm, d);
    }
    base[lane]       = k / (sqrtf(sk) + 1e-6f);
    base[192 + lane] = m / (sqrtf(sm) + 1e-6f);
}

// ---------------------------------------------------------------------------
// Kernel 2: sequential recurrence — barrier-free, LDS-free.
// 256 blocks (rt-major: bid = rt*64 + b so the 4 blocks sharing batch b land
// on the same XCD's L2), 256 threads = 16 rows x 16 lanes x 4 cols in regs.
// Per step: each lane loads its own float4 slices of (kn,q,mn) + scalar v
// straight from global (1KB unique/block, L1/L2-hit), distance-3 prefetch
// via 4 named register sets; reductions are 4-stage DPP rotate-adds.
// ---------------------------------------------------------------------------
__global__ __launch_bounds__(256) void recur_kernel(const float* __restrict__ proj,
                                                    const float* __restrict__ S0,
                                                    const float* __restrict__ M0,
                                                    const float* __restrict__ BSmat,
                                                    const float* __restrict__ BMmat,
                                                    float* __restrict__ outp,
                                                    float* __restrict__ Sout,
                                                    float* __restrict__ Mout) {
    const int tid = threadIdx.x;
    const int b   = blockIdx.x & 63;     // batch (inner -> sharers on same XCD)
    const int rt  = blockIdx.x >> 6;     // row tile
    const int rl  = tid >> 4;            // local row 0..15
    const int i   = (rt << 4) + rl;      // global row 0..63
    const int l16 = tid & 15;
    const int j0  = l16 << 2;            // first of 4 owned columns

    float S[4], Mr[4], BSr[4], BMr[4];
    const size_t smoff = ((size_t)b * NDIM + i) * NDIM + j0;
    { float4 t4 = *(const float4*)&S0[smoff];                    S[0]=t4.x;  S[1]=t4.y;  S[2]=t4.z;  S[3]=t4.w;  }
    { float4 t4 = *(const float4*)&M0[smoff];                    Mr[0]=t4.x; Mr[1]=t4.y; Mr[2]=t4.z; Mr[3]=t4.w; }
    { float4 t4 = *(const float4*)&BSmat[(size_t)i * NDIM + j0]; BSr[0]=t4.x;BSr[1]=t4.y;BSr[2]=t4.z;BSr[3]=t4.w;}
    { float4 t4 = *(const float4*)&BMmat[(size_t)i * NDIM + j0]; BMr[0]=t4.x;BMr[1]=t4.y;BMr[2]=t4.z;BMr[3]=t4.w;}

    const float* pb = proj + (size_t)b * PROJW;

    // one scan step on the current register set
    auto step = [&](int t, float4 kn4, float4 q4, float4 mn4, float v_i) {
        const float kr[4] = {kn4.x, kn4.y, kn4.z, kn4.w};   // pre-normalized k
        const float qr[4] = {q4.x,  q4.y,  q4.z,  q4.w};
        const float mr[4] = {mn4.x, mn4.y, mn4.z, mn4.w};   // pre-normalized m

        // dots on OLD S, M
        float Mk = 0.f, Sk = 0.f, Mm = 0.f;
        #pragma unroll
        for (int c = 0; c < 4; ++c) {
            Mk = fmaf(Mr[c], kr[c], Mk);
            Sk = fmaf(S[c],  kr[c], Sk);
            Mm = fmaf(Mr[c], mr[c], Mm);
        }
        Mk = rowsum16(Mk); Sk = rowsum16(Sk); Mm = rowsum16(Mm);
        const float sd = v_i - Sk;                 // s_delta[i]

        // G_S and S update
        #pragma unroll
        for (int c = 0; c < 4; ++c) {
            const float gs = sigmoidf_(fmaf(Mk, kr[c], Mr[c]) + BSr[c]);
            S[c] = fmaf(gs, S[c], sd * kr[c]);
        }
        // dots on NEW S
        float Sm = 0.f, Sq = 0.f;
        #pragma unroll
        for (int c = 0; c < 4; ++c) {
            Sm = fmaf(S[c], mr[c], Sm);
            Sq = fmaf(S[c], qr[c], Sq);
        }
        Sm = rowsum16(Sm); Sq = rowsum16(Sq);
        const float md = sd - Mm;                  // m_delta[i]

        // G_M and M update
        #pragma unroll
        for (int c = 0; c < 4; ++c) {
            const float gm = sigmoidf_(fmaf(Sm, mr[c], S[c]) + BMr[c]);
            Mr[c] = fmaf(gm, Mr[c], md * mr[c]);
        }
        // out = Sq * silu(Sq)
        if (l16 == 0) {
            outp[(size_t)t * (BATCH * NDIM) + b * NDIM + i] = Sq * Sq * sigmoidf_(Sq);
        }
    };

#define DECL_SET(s) float4 kn##s, q##s, mn##s; float vi##s;
#define LOAD_SET(s, tt) { \
        const int t_ = ((tt) < T_STEPS) ? (tt) : (T_STEPS - 1); \
        const float* r_ = pb + (size_t)t_ * STEPSTRIDE; \
        kn##s = *(const float4*)(r_ + j0); \
        q##s  = *(const float4*)(r_ + 128 + j0); \
        mn##s = *(const float4*)(r_ + 192 + j0); \
        vi##s = r_[64 + i]; }

    DECL_SET(0) DECL_SET(1) DECL_SET(2) DECL_SET(3)
    LOAD_SET(0, 0) LOAD_SET(1, 1) LOAD_SET(2, 2) LOAD_SET(3, 3)

    for (int t = 0; t < T_STEPS; t += 4) {
        step(t + 0, kn0, q0, mn0, vi0); LOAD_SET(0, t + 4);
        step(t + 1, kn1, q1, mn1, vi1); LOAD_SET(1, t + 5);
        step(t + 2, kn2, q2, mn2, vi2); LOAD_SET(2, t + 6);
        step(t + 3, kn3, q3, mn3, vi3); LOAD_SET(3, t + 7);
    }
#undef DECL_SET
#undef LOAD_SET

    { float4 o = {S[0], S[1], S[2], S[3]};     *(float4*)&Sout[smoff] = o; }
    { float4 o = {Mr[0], Mr[1], Mr[2], Mr[3]}; *(float4*)&Mout[smoff] = o; }
}

// ---------------------------------------------------------------------------
extern "C" void kernel_launch(void* const* d_in, const int* in_sizes, int n_in,
                              void* d_out, int out_size, void* d_ws, size_t ws_size,
                              hipStream_t stream) {
    const float* x   = (const float*)d_in[0];   // (T,B,DIM) f32
    const float* S0  = (const float*)d_in[1];   // (B,N,N)
    const float* M0  = (const float*)d_in[2];   // (B,N,N)
    const float* W   = (const float*)d_in[3];   // (4N,DIM)
    const float* BS  = (const float*)d_in[4];   // (N,N)
    const float* BMb = (const float*)d_in[5];   // (N,N)
    float* out = (float*)d_out;

    float* proj = (float*)d_ws;                 // T*B*256 f32 = 64 MB

    dim3 g1(512, 2), b1(256);
    proj_gemm<<<g1, b1, 0, stream>>>(x, W, proj);

    normalize_km<<<dim3(T_STEPS * BATCH / 4), dim3(256), 0, stream>>>(proj);

    float* Sout = out + (size_t)T_STEPS * BATCH * NDIM;
    float* Mout = Sout + (size_t)BATCH * NDIM * NDIM;
    recur_kernel<<<dim3(BATCH * 4), dim3(256), 0, stream>>>(proj, S0, M0, BS, BMb,
                                                            out, Sout, Mout);
}

// Round 6
// 734.467 us; speedup vs baseline: 2.4486x; 1.1788x over previous
//
#include <hip/hip_runtime.h>
#include <cstddef>

// Problem constants (from reference): T=1024, B=64, DIM=512, N=64
#define T_STEPS 1024
#define BATCH   64
#define DIMK    512
#define NDIM    64
#define PROJW   256   // 4*N
#define STEPSTRIDE (BATCH * PROJW)

// fast sigmoid: v_exp + v_rcp (1-2 ulp), avoids the IEEE div sequence
// (v_div_scale/fmas/fixup ~10 dependent ops) that 1.0f/x emits without fast-math.
__device__ __forceinline__ float sigmoidf_(float x) {
    return __builtin_amdgcn_rcpf(1.0f + __expf(-x));
}

// DPP row-rotate move: dst lane i <- src lane (i+N) mod 16 (within each 16-lane row)
template<int CTRL>
__device__ __forceinline__ float dpp_mov(float x) {
    return __int_as_float(__builtin_amdgcn_update_dpp(
        0, __float_as_int(x), CTRL, 0xF, 0xF, true));
}
// 32-lane allreduce: 4 DPP rotate-adds within each 16-lane row, then one
// cross-16 exchange via shfl_xor (single ds-op stage).
__device__ __forceinline__ float redrow32(float x) {
    x += dpp_mov<0x128>(x);
    x += dpp_mov<0x124>(x);
    x += dpp_mov<0x122>(x);
    x += dpp_mov<0x121>(x);
    x += __shfl_xor(x, 16);
    return x;
}

// ---------------------------------------------------------------------------
// Kernel 1: projection GEMM  C[M=T*B][256] = X[M][512] * W[256][512]^T
// 128x128 tile, BK=16, 256 threads, 8x8 acc/thread, 2x2 blocked-cyclic
// fragment layout. (unchanged from round 4 — next round's target)
// ---------------------------------------------------------------------------
__global__ __launch_bounds__(256) void proj_gemm(const float* __restrict__ X,
                                                 const float* __restrict__ W,
                                                 float* __restrict__ C) {
    __shared__ float As[16][132];
    __shared__ float Bs[16][132];
    const int tid  = threadIdx.x;
    const int row0 = blockIdx.x * 128;            // 512 row tiles
    const int col0 = blockIdx.y * 128;            // 2 col tiles
    const int tx4  = (tid & 15) << 2;
    const int ty4  = (tid >> 4) << 2;
    const int lm   = tid >> 2;                    // 0..63 staging row
    const int lk   = (tid & 3) << 2;              // 0,4,8,12 staging k

    const float* Arow0 = X + (size_t)(row0 + lm)      * DIMK + lk;
    const float* Arow1 = X + (size_t)(row0 + lm + 64) * DIMK + lk;
    const float* Brow0 = W + (size_t)(col0 + lm)      * DIMK + lk;
    const float* Brow1 = W + (size_t)(col0 + lm + 64) * DIMK + lk;

    float acc[8][8] = {};
    float4 pa0, pa1, pb0, pb1;

    pa0 = *(const float4*)(Arow0);
    pa1 = *(const float4*)(Arow1);
    pb0 = *(const float4*)(Brow0);
    pb1 = *(const float4*)(Brow1);

    for (int tile = 0; tile < DIMK / 16; ++tile) {
        __syncthreads();   // previous tile's readers done
        As[lk+0][lm]    = pa0.x; As[lk+1][lm]    = pa0.y; As[lk+2][lm]    = pa0.z; As[lk+3][lm]    = pa0.w;
        As[lk+0][lm+64] = pa1.x; As[lk+1][lm+64] = pa1.y; As[lk+2][lm+64] = pa1.z; As[lk+3][lm+64] = pa1.w;
        Bs[lk+0][lm]    = pb0.x; Bs[lk+1][lm]    = pb0.y; Bs[lk+2][lm]    = pb0.z; Bs[lk+3][lm]    = pb0.w;
        Bs[lk+0][lm+64] = pb1.x; Bs[lk+1][lm+64] = pb1.y; Bs[lk+2][lm+64] = pb1.z; Bs[lk+3][lm+64] = pb1.w;
        __syncthreads();
        if (tile + 1 < DIMK / 16) {
            const int kb = (tile + 1) * 16;
            pa0 = *(const float4*)(Arow0 + kb);
            pa1 = *(const float4*)(Arow1 + kb);
            pb0 = *(const float4*)(Brow0 + kb);
            pb1 = *(const float4*)(Brow1 + kb);
        }
        #pragma unroll 8
        for (int k = 0; k < 16; ++k) {
            const float4 a0v = *(const float4*)&As[k][ty4];
            const float4 a1v = *(const float4*)&As[k][64 + ty4];
            const float4 b0v = *(const float4*)&Bs[k][tx4];
            const float4 b1v = *(const float4*)&Bs[k][64 + tx4];
            const float a[8]  = {a0v.x, a0v.y, a0v.z, a0v.w, a1v.x, a1v.y, a1v.z, a1v.w};
            const float bb[8] = {b0v.x, b0v.y, b0v.z, b0v.w, b1v.x, b1v.y, b1v.z, b1v.w};
            #pragma unroll
            for (int i2 = 0; i2 < 8; ++i2)
                #pragma unroll
                for (int j2 = 0; j2 < 8; ++j2)
                    acc[i2][j2] = fmaf(a[i2], bb[j2], acc[i2][j2]);
        }
    }

    #pragma unroll
    for (int h = 0; h < 2; ++h) {
        #pragma unroll
        for (int r = 0; r < 4; ++r) {
            const size_t R = (size_t)(row0 + h * 64 + ty4 + r) * PROJW + col0;
            float4 o0 = {acc[h*4+r][0], acc[h*4+r][1], acc[h*4+r][2], acc[h*4+r][3]};
            float4 o1 = {acc[h*4+r][4], acc[h*4+r][5], acc[h*4+r][6], acc[h*4+r][7]};
            *(float4*)&C[R + tx4]      = o0;
            *(float4*)&C[R + 64 + tx4] = o1;
        }
    }
}

// ---------------------------------------------------------------------------
// Kernel 1.5: normalize k (cols 0..63) and m (cols 192..255) of proj in place.
// ---------------------------------------------------------------------------
__global__ __launch_bounds__(256) void normalize_km(float* __restrict__ proj) {
    const int p    = blockIdx.x * 4 + (threadIdx.x >> 6);  // (t,b) pair index
    const int lane = threadIdx.x & 63;
    float* base = proj + (size_t)p * PROJW;
    const float k = base[lane];
    const float m = base[192 + lane];
    float sk = k * k, sm = m * m;
    #pragma unroll
    for (int d = 1; d < 64; d <<= 1) {
        sk += __shfl_xor(sk, d);
        sm += __shfl_xor(sm, d);
    }
    base[lane]       = k / (sqrtf(sk) + 1e-6f);
    base[192 + lane] = m / (sqrtf(sm) + 1e-6f);
}

// ---------------------------------------------------------------------------
// Kernel 2: sequential recurrence — barrier-free, LDS-free, 2 waves/SIMD.
// Re-partition: 32 lanes per state row, 2 cols per lane -> 4096 rows x 32 =
// 2048 waves = 8 waves/CU = 2/SIMD (was 1/SIMD): doubles latency hiding of
// the serial dependency chain. 512 blocks x 256 threads (8 rows/block).
// bid = oct*64 + b  ->  all 8 blocks of batch b land on XCD b%8 (L2 share).
// Reductions: 4 DPP stages + 1 shfl_xor(16). Sigmoid via v_rcp (no IEEE div).
// Distance-3 prefetch via 4 named register sets (float2 slices).
// ---------------------------------------------------------------------------
__global__ __launch_bounds__(256) void recur_kernel(const float* __restrict__ proj,
                                                    const float* __restrict__ S0,
                                                    const float* __restrict__ M0,
                                                    const float* __restrict__ BSmat,
                                                    const float* __restrict__ BMmat,
                                                    float* __restrict__ outp,
                                                    float* __restrict__ Sout,
                                                    float* __restrict__ Mout) {
    const int tid = threadIdx.x;
    const int b   = blockIdx.x & 63;     // batch (inner -> sharers on same XCD)
    const int oct = blockIdx.x >> 6;     // row octet 0..7
    const int lr  = tid >> 5;            // local row 0..7 (one 32-lane group each)
    const int i   = (oct << 3) + lr;     // global row 0..63
    const int l32 = tid & 31;
    const int j0  = l32 << 1;            // first of 2 owned columns

    float S[2], Mr[2], BSr[2], BMr[2];
    const size_t smoff = ((size_t)b * NDIM + i) * NDIM + j0;
    { float2 t2 = *(const float2*)&S0[smoff];                    S[0]=t2.x;  S[1]=t2.y;  }
    { float2 t2 = *(const float2*)&M0[smoff];                    Mr[0]=t2.x; Mr[1]=t2.y; }
    { float2 t2 = *(const float2*)&BSmat[(size_t)i * NDIM + j0]; BSr[0]=t2.x;BSr[1]=t2.y;}
    { float2 t2 = *(const float2*)&BMmat[(size_t)i * NDIM + j0]; BMr[0]=t2.x;BMr[1]=t2.y;}

    const float* pb = proj + (size_t)b * PROJW;

    // one scan step on the current register set
    auto step = [&](int t, float2 kn2, float2 q2, float2 mn2, float v_i) {
        // dots on OLD S, M (2-level: mul + fma)
        float Mk = Mr[0] * kn2.x; Mk = fmaf(Mr[1], kn2.y, Mk);
        float Sk = S[0]  * kn2.x; Sk = fmaf(S[1],  kn2.y, Sk);
        float Mm = Mr[0] * mn2.x; Mm = fmaf(Mr[1], mn2.y, Mm);
        Mk = redrow32(Mk); Sk = redrow32(Sk); Mm = redrow32(Mm);
        const float sd = v_i - Sk;                 // s_delta[i]

        // G_S and S update
        {
            const float g0 = sigmoidf_(fmaf(Mk, kn2.x, Mr[0]) + BSr[0]);
            const float g1 = sigmoidf_(fmaf(Mk, kn2.y, Mr[1]) + BSr[1]);
            S[0] = fmaf(g0, S[0], sd * kn2.x);
            S[1] = fmaf(g1, S[1], sd * kn2.y);
        }
        // dots on NEW S
        float Sm = S[0] * mn2.x; Sm = fmaf(S[1], mn2.y, Sm);
        float Sq = S[0] * q2.x;  Sq = fmaf(S[1], q2.y,  Sq);
        Sm = redrow32(Sm); Sq = redrow32(Sq);
        const float md = sd - Mm;                  // m_delta[i]

        // G_M and M update
        {
            const float g0 = sigmoidf_(fmaf(Sm, mn2.x, S[0]) + BMr[0]);
            const float g1 = sigmoidf_(fmaf(Sm, mn2.y, S[1]) + BMr[1]);
            Mr[0] = fmaf(g0, Mr[0], md * mn2.x);
            Mr[1] = fmaf(g1, Mr[1], md * mn2.y);
        }
        // out = Sq * silu(Sq)
        if (l32 == 0) {
            outp[(size_t)t * (BATCH * NDIM) + b * NDIM + i] = Sq * Sq * sigmoidf_(Sq);
        }
    };

#define DECL_SET(s) float2 kn##s, q##s, mn##s; float vi##s;
#define LOAD_SET(s, tt) { \
        const int t_ = ((tt) < T_STEPS) ? (tt) : (T_STEPS - 1); \
        const float* r_ = pb + (size_t)t_ * STEPSTRIDE; \
        kn##s = *(const float2*)(r_ + j0); \
        q##s  = *(const float2*)(r_ + 128 + j0); \
        mn##s = *(const float2*)(r_ + 192 + j0); \
        vi##s = r_[64 + i]; }

    DECL_SET(0) DECL_SET(1) DECL_SET(2) DECL_SET(3)
    LOAD_SET(0, 0) LOAD_SET(1, 1) LOAD_SET(2, 2) LOAD_SET(3, 3)

    for (int t = 0; t < T_STEPS; t += 4) {
        step(t + 0, kn0, q0, mn0, vi0); LOAD_SET(0, t + 4);
        step(t + 1, kn1, q1, mn1, vi1); LOAD_SET(1, t + 5);
        step(t + 2, kn2, q2, mn2, vi2); LOAD_SET(2, t + 6);
        step(t + 3, kn3, q3, mn3, vi3); LOAD_SET(3, t + 7);
    }
#undef DECL_SET
#undef LOAD_SET

    { float2 o = {S[0], S[1]};   *(float2*)&Sout[smoff] = o; }
    { float2 o = {Mr[0], Mr[1]}; *(float2*)&Mout[smoff] = o; }
}

// ---------------------------------------------------------------------------
extern "C" void kernel_launch(void* const* d_in, const int* in_sizes, int n_in,
                              void* d_out, int out_size, void* d_ws, size_t ws_size,
                              hipStream_t stream) {
    const float* x   = (const float*)d_in[0];   // (T,B,DIM) f32
    const float* S0  = (const float*)d_in[1];   // (B,N,N)
    const float* M0  = (const float*)d_in[2];   // (B,N,N)
    const float* W   = (const float*)d_in[3];   // (4N,DIM)
    const float* BS  = (const float*)d_in[4];   // (N,N)
    const float* BMb = (const float*)d_in[5];   // (N,N)
    float* out = (float*)d_out;

    float* proj = (float*)d_ws;                 // T*B*256 f32 = 64 MB

    dim3 g1(512, 2), b1(256);
    proj_gemm<<<g1, b1, 0, stream>>>(x, W, proj);

    normalize_km<<<dim3(T_STEPS * BATCH / 4), dim3(256), 0, stream>>>(proj);

    float* Sout = out + (size_t)T_STEPS * BATCH * NDIM;
    float* Mout = Sout + (size_t)BATCH * NDIM * NDIM;
    recur_kernel<<<dim3(BATCH * 8), dim3(256), 0, stream>>>(proj, S0, M0, BS, BMb,
                                                            out, Sout, Mout);
}